// Round 13
// baseline (261.857 us; speedup 1.0000x reference)
//
#include <hip/hip_runtime.h>
#include <hip/hip_bf16.h>
#include <stdint.h>

typedef unsigned char u8;
typedef unsigned int u32;
typedef unsigned long long u64;
typedef long i64;
typedef i64 i64x2 __attribute__((ext_vector_type(2)));
typedef float f32x4 __attribute__((ext_vector_type(4)));

#define LOGSQRT2PI 0.9189385332046727f
#define SB0() __builtin_amdgcn_sched_barrier(0)
#define MFMA8(A, B, C) __builtin_amdgcn_mfma_f32_16x16x32_fp8_fp8(A, B, C, 0, 0, 0)

__device__ __forceinline__ u8 to_fp8(float v) {
    return (u8)(__builtin_amdgcn_cvt_pk_fp8_f32(v, 0.f, 0, false) & 0xff);
}

// ---- merged weight prep (r12-proven): W = mu+(1e-6+softplus(p))*eps ;
// ---- Wt[n][k] fp8 e4m3 ; lqw/lpw fp32-exact atomics ----
__device__ __forceinline__ void prep_body(const float* __restrict__ mu,
        const float* __restrict__ p, const float* __restrict__ eps,
        u8* __restrict__ Wt, int N, int Npad, float* __restrict__ osc,
        int vb, int nblocks) {
    int total = 512 * Npad;
    float lqw = 0.f, lpw = 0.f;
    for (int idx = vb * 256 + threadIdx.x; idx < total; idx += nblocks * 256) {
        int k = idx / Npad, n = idx - k * Npad;
        float w = 0.f;
        if (n < N) {
            int src = k * N + n;
            float m = mu[src], e = eps[src];
            float sd = 1e-6f + log1pf(expf(p[src]));
            w = m + sd * e;
            float z = (w - m) / sd;
            lqw += -LOGSQRT2PI - logf(sd) - 0.5f * z * z;
            lpw += -LOGSQRT2PI - 0.5f * w * w;
        }
        Wt[n * 512 + k] = to_fp8(w);
    }
    #pragma unroll
    for (int off = 32; off; off >>= 1) {
        lqw += __shfl_down(lqw, off);
        lpw += __shfl_down(lpw, off);
    }
    if ((threadIdx.x & 63) == 0) {
        atomicAdd(&osc[0], lqw);
        atomicAdd(&osc[1], lpw);
    }
}

__global__ void k_prep_all(const float* __restrict__ mu1, const float* __restrict__ p1,
                           const float* __restrict__ e1,
                           const float* __restrict__ mu2, const float* __restrict__ p2,
                           const float* __restrict__ e2,
                           const float* __restrict__ mu3, const float* __restrict__ p3,
                           const float* __restrict__ e3,
                           u8* __restrict__ Wt1, u8* __restrict__ Wt2,
                           u8* __restrict__ Wt3, float* __restrict__ osc) {
    int b = blockIdx.x;
    if (b < 256)      prep_body(mu1, p1, e1, Wt1, 512, 512, osc, b, 256);
    else if (b < 512) prep_body(mu2, p2, e2, Wt2, 512, 512, osc, b - 256, 256);
    else              prep_body(mu3, p3, e3, Wt3, 10,  16,  osc, b - 512, 16);
}

// ---- x fp32 -> fp8 (r12-proven) ----
__global__ void k_cvt8(const float4* __restrict__ in, uint2* __restrict__ out, int n8) {
    int stride = gridDim.x * blockDim.x;
    for (int i = blockIdx.x * blockDim.x + threadIdx.x; i < n8; i += stride) {
        float4 a = in[2 * i], b = in[2 * i + 1];
        u32 lo = __builtin_amdgcn_cvt_pk_fp8_f32(a.x, a.y, 0, false);
        lo = __builtin_amdgcn_cvt_pk_fp8_f32(a.z, a.w, (int)lo, true);
        u32 hi = __builtin_amdgcn_cvt_pk_fp8_f32(b.x, b.y, 0, false);
        hi = __builtin_amdgcn_cvt_pk_fp8_f32(b.z, b.w, (int)hi, true);
        out[i] = make_uint2(lo, hi);
    }
}

// ============================================================================
// Register-stationary-B GEMV-style fp8 GEMM.  NO LDS staging, NO barriers,
// NO manual vmcnt: each wave is an independent stream.
//   Block 256 thr = 4 waves; wave w owns 32 output cols c0 = cg*128 + w*32,
//   B (32 cols x 512 K fp8) lives in 64 VGPR (fragment layout, loaded once).
//   Grid = 4 col-groups x 256 m-blocks; block processes 256 rows = 16 chunks
//   of 16 rows; chunks register-double-buffered (static names aA/aB).
// A-fragment gather from ROW-MAJOR global (r12 permuted-k layout): lane l
//   reads 16B at row (l&15), k-window (l>>4)*16 of each K=64 tile -> a wave
//   touches 16 full 64B lines per instruction (perfect coalescing).  One 16B
//   reg = two MFMA k-steps (.x/.y halves); A and B use the identical window
//   map so contraction pairs identical global k (r12-validated, absmax 5.75).
// Per chunk: 8 global_load_dwordx4 + 32 MFMA (~160cy) + epilogue.
// Epilogue via wave-private padded scratch (row-major [16][stride 40] fp8,
//   bank-spread; wave-private => lgkmcnt+sched_barrier only, no s_barrier):
//   g1: rows re-read as u64 -> coalesced 8B h1 stores.
//   g2: h2 chunk's 32 cols == exactly one K=32 y-MFMA vs W3 frag -> 4
//       atomicAdd/lane (4 col-group writers per y element).
// ============================================================================
template<bool FUSE3>
__global__ __launch_bounds__(256, 2)
void k_gv(const u8* __restrict__ A, const u8* __restrict__ Bt,
          u8* __restrict__ C, const u8* __restrict__ W3t,
          float* __restrict__ Y) {
    __shared__ u8 scr_all[4 * 768];
    const int tid = threadIdx.x;
    const int l = tid & 63, w = tid >> 6;
    const int r = l & 15, kq = l >> 4;
    u8* scr = &scr_all[w * 768];

    const int cg = blockIdx.x >> 8;        // 0..3
    const int mb = blockIdx.x & 255;       // 0..255
    const int c0 = cg * 128 + w * 32;
    const long m0 = (long)mb * 256;

    // ---- B resident in registers: 2 col-groups x 8 K-tiles x 16B ----
    i64x2 b[2][8];
    #pragma unroll
    for (int jg = 0; jg < 2; jg++)
        #pragma unroll
        for (int kt = 0; kt < 8; kt++)
            b[jg][kt] = *(const i64x2*)(Bt + (long)(c0 + jg * 16 + r) * 512 + kt * 64 + kq * 16);
    i64 w3f = 0;
    if (FUSE3) w3f = *(const i64*)(W3t + r * 512 + c0 + kq * 8);

    #define ALOAD(DST, CC) { _Pragma("unroll")                                 \
        for (int kt = 0; kt < 8; kt++)                                         \
            DST[kt] = *(const i64x2*)(A + (m0 + (CC) * 16 + r) * 512 + kt * 64 + kq * 16); }

    #define BODY(AA, CC) {                                                     \
        f32x4 acc0 = (f32x4){0.f, 0.f, 0.f, 0.f};                              \
        f32x4 acc1 = (f32x4){0.f, 0.f, 0.f, 0.f};                              \
        _Pragma("unroll")                                                      \
        for (int kt = 0; kt < 8; kt++) {                                       \
            acc0 = MFMA8(AA[kt].x, b[0][kt].x, acc0);                          \
            acc0 = MFMA8(AA[kt].y, b[0][kt].y, acc0);                          \
            acc1 = MFMA8(AA[kt].x, b[1][kt].x, acc1);                          \
            acc1 = MFMA8(AA[kt].y, b[1][kt].y, acc1);                          \
        }                                                                      \
        _Pragma("unroll")                                                      \
        for (int q = 0; q < 4; q++) {                                          \
            scr[(kq * 4 + q) * 40 + r]      = to_fp8(fmaxf(acc0[q], 0.f));     \
            scr[(kq * 4 + q) * 40 + 16 + r] = to_fp8(fmaxf(acc1[q], 0.f));     \
        }                                                                      \
        asm volatile("s_waitcnt lgkmcnt(0)" ::: "memory"); SB0();              \
        if (!FUSE3) {                                                          \
            int row = l >> 2;                                                  \
            u64 v = *(const u64*)&scr[row * 40 + (l & 3) * 8];                 \
            *(u64*)(C + (m0 + (CC) * 16 + row) * 512 + c0 + (l & 3) * 8) = v;  \
        } else {                                                               \
            i64 a3 = *(const i64*)&scr[r * 40 + kq * 8];                       \
            f32x4 y4 = (f32x4){0.f, 0.f, 0.f, 0.f};                            \
            y4 = MFMA8(a3, w3f, y4);                                           \
            if (r < 10) {                                                      \
                _Pragma("unroll")                                              \
                for (int q = 0; q < 4; q++)                                    \
                    atomicAdd(Y + (m0 + (CC) * 16 + kq * 4 + q) * 10 + r, y4[q]); \
            }                                                                  \
        }                                                                      \
        asm volatile("s_waitcnt lgkmcnt(0)" ::: "memory"); SB0();              \
    }

    i64x2 aA[8], aB[8];
    ALOAD(aA, 0);
    #pragma unroll
    for (int cc = 0; cc < 8; ++cc) {
        ALOAD(aB, 2 * cc + 1);
        BODY(aA, 2 * cc);
        if (cc < 7) ALOAD(aA, 2 * cc + 2);
        BODY(aB, 2 * cc + 1);
    }
    #undef ALOAD
    #undef BODY
}

extern "C" void kernel_launch(void* const* d_in, const int* in_sizes, int n_in,
                              void* d_out, int out_size, void* d_ws, size_t ws_size,
                              hipStream_t stream) {
    const float* x   = (const float*)d_in[0];
    const float* mu1 = (const float*)d_in[1];
    const float* p1  = (const float*)d_in[2];
    const float* e1  = (const float*)d_in[3];
    const float* mu2 = (const float*)d_in[4];
    const float* p2  = (const float*)d_in[5];
    const float* e2  = (const float*)d_in[6];
    const float* mu3 = (const float*)d_in[7];
    const float* p3  = (const float*)d_in[8];
    const float* e3  = (const float*)d_in[9];
    float* out = (float*)d_out;

    const int B = 65536, D = 512, DO = 10;

    char* ws = (char*)d_ws;
    u8* Wt1 = (u8*)(ws);                       // 256 KB
    u8* Wt2 = (u8*)(ws + 262144);              // 256 KB
    u8* Wt3 = (u8*)(ws + 524288);              // 8 KB
    u8* xb  = (u8*)(ws + 1048576);             // 32 MB
    u8* h1  = (u8*)(ws + 1048576 + 33554432);  // 32 MB

    float* osc = out + (long)B * DO;

    hipMemsetAsync(out, 0, (size_t)out_size * sizeof(float), stream);
    hipLaunchKernelGGL(k_prep_all, dim3(528), dim3(256), 0, stream,
                       mu1, p1, e1, mu2, p2, e2, mu3, p3, e3, Wt1, Wt2, Wt3, osc);
    hipLaunchKernelGGL(k_cvt8, dim3(2048), dim3(256), 0, stream,
                       (const float4*)x, (uint2*)xb, B * D / 8);
    hipLaunchKernelGGL((k_gv<false>), dim3(1024), dim3(256), 0, stream,
                       xb, Wt1, h1, (const u8*)nullptr, (float*)nullptr);
    hipLaunchKernelGGL((k_gv<true>), dim3(1024), dim3(256), 0, stream,
                       h1, Wt2, (u8*)nullptr, Wt3, out);
}

// Round 14
// 165.016 us; speedup vs baseline: 1.5869x; 1.5869x over previous
//
#include <hip/hip_runtime.h>
#include <hip/hip_bf16.h>
#include <stdint.h>

typedef unsigned char u8;
typedef unsigned int u32;
typedef long i64;
typedef i64 i64x2 __attribute__((ext_vector_type(2)));
typedef float f32x4 __attribute__((ext_vector_type(4)));

#define LOGSQRT2PI 0.9189385332046727f
#define SB0() __builtin_amdgcn_sched_barrier(0)
#define MFMA8(A, B, C) __builtin_amdgcn_mfma_f32_16x16x32_fp8_fp8(A, B, C, 0, 0, 0)

__device__ __forceinline__ void gload_lds16(const void* g, void* l) {
    __builtin_amdgcn_global_load_lds((__attribute__((address_space(1))) void*)g,
                                     (__attribute__((address_space(3))) void*)l,
                                     16, 0, 0);
}

__device__ __forceinline__ u8 to_fp8(float v) {
    return (u8)(__builtin_amdgcn_cvt_pk_fp8_f32(v, 0.f, 0, false) & 0xff);
}

// ---- merged weight prep (r12-proven): W = mu+(1e-6+softplus(p))*eps ;
// ---- Wt[n][k] fp8 e4m3 ; lqw/lpw fp32-exact atomics ----
__device__ __forceinline__ void prep_body(const float* __restrict__ mu,
        const float* __restrict__ p, const float* __restrict__ eps,
        u8* __restrict__ Wt, int N, int Npad, float* __restrict__ osc,
        int vb, int nblocks) {
    int total = 512 * Npad;
    float lqw = 0.f, lpw = 0.f;
    for (int idx = vb * 256 + threadIdx.x; idx < total; idx += nblocks * 256) {
        int k = idx / Npad, n = idx - k * Npad;
        float w = 0.f;
        if (n < N) {
            int src = k * N + n;
            float m = mu[src], e = eps[src];
            float sd = 1e-6f + log1pf(expf(p[src]));
            w = m + sd * e;
            float z = (w - m) / sd;
            lqw += -LOGSQRT2PI - logf(sd) - 0.5f * z * z;
            lpw += -LOGSQRT2PI - 0.5f * w * w;
        }
        Wt[n * 512 + k] = to_fp8(w);
    }
    #pragma unroll
    for (int off = 32; off; off >>= 1) {
        lqw += __shfl_down(lqw, off);
        lpw += __shfl_down(lpw, off);
    }
    if ((threadIdx.x & 63) == 0) {
        atomicAdd(&osc[0], lqw);
        atomicAdd(&osc[1], lpw);
    }
}

__global__ void k_prep_all(const float* __restrict__ mu1, const float* __restrict__ p1,
                           const float* __restrict__ e1,
                           const float* __restrict__ mu2, const float* __restrict__ p2,
                           const float* __restrict__ e2,
                           const float* __restrict__ mu3, const float* __restrict__ p3,
                           const float* __restrict__ e3,
                           u8* __restrict__ Wt1, u8* __restrict__ Wt2,
                           u8* __restrict__ Wt3, float* __restrict__ osc) {
    int b = blockIdx.x;
    if (b < 256)      prep_body(mu1, p1, e1, Wt1, 512, 512, osc, b, 256);
    else if (b < 512) prep_body(mu2, p2, e2, Wt2, 512, 512, osc, b - 256, 256);
    else              prep_body(mu3, p3, e3, Wt3, 10,  16,  osc, b - 512, 16);
}

// ---- x fp32 -> fp8 (r12-proven) ----
__global__ void k_cvt8(const float4* __restrict__ in, uint2* __restrict__ out, int n8) {
    int stride = gridDim.x * blockDim.x;
    for (int i = blockIdx.x * blockDim.x + threadIdx.x; i < n8; i += stride) {
        float4 a = in[2 * i], b = in[2 * i + 1];
        u32 lo = __builtin_amdgcn_cvt_pk_fp8_f32(a.x, a.y, 0, false);
        lo = __builtin_amdgcn_cvt_pk_fp8_f32(a.z, a.w, (int)lo, true);
        u32 hi = __builtin_amdgcn_cvt_pk_fp8_f32(b.x, b.y, 0, false);
        hi = __builtin_amdgcn_cvt_pk_fp8_f32(b.z, b.w, (int)hi, true);
        out[i] = make_uint2(lo, hi);
    }
}

// ============================================================================
// Fully-fused fp8 3-layer kernel.  Block = 4 waves x 32 rows = 128 rows; grid
// 512; 80 KB LDS -> 2 blocks/CU; launch_bounds(256,2) (peak ~180 VGPR,
// rowgroups serialized).
//   xf: x fragments loaded ONCE from xb (r12 permuted-k gather: lane l = row
//       l&15, k-window (l>>4)*16 per K=64 tile; wave = 16 full 64B lines).
//   Weights: per 128-col tile staged to LDS in fragment-chunk layout (chunk
//       (jg,kt) = 1KB at (kt*8+jg)*1024; 16 gload_lds16/thread), vmcnt(0) +
//       barrier -- the MFMA loop then touches ONLY LDS + registers (no global
//       latency inside; end-of-compute barrier protects Wbuf reuse, ds reads
//       drained naturally by last MFMA's lgkm wait).
//   h1 (32 rows x 512 fp8) in registers via wave-private swizzled scratch
//       transpose (phys16Bchunk = cc ^ (row&7); r8-proven).  h1/h2 never
//       touch HBM.  Layer 3 fused per tile vs W3 frags; y stored DIRECTLY
//       (full K per block: no atomics, no zeroing).
// ============================================================================
__global__ __launch_bounds__(256, 2)
void k_f8(const u8* __restrict__ xb, const u8* __restrict__ W1t,
          const u8* __restrict__ W2t, const u8* __restrict__ W3t,
          float* __restrict__ Y) {
    __shared__ __align__(16) u8 L[81920];   // 64KB Wbuf + 4 x 4KB scr
    const int tid = threadIdx.x;
    const int l = tid & 63, w = tid >> 6;
    const int r = l & 15, kq = l >> 4;
    const int l16 = l * 16;
    const long m0 = (long)blockIdx.x * 128 + w * 32;
    u8* scr = &L[65536 + w * 4096];         // [32 rows][128 cols] fp8, swizzled

    #define STAGEW(WT, NT) { _Pragma("unroll")                                 \
        for (int i = 0; i < 16; i++) {                                         \
            const int c = w * 16 + i;                                          \
            gload_lds16((WT) + ((NT) * 128 + (c & 7) * 16 + r) * 512           \
                              + (c >> 3) * 64 + kq * 16,                       \
                        &L[c * 1024 + l16]);                                   \
        } }

    // MFMA loop for one rowgroup: 8 jg x 8 kt x 2 halves = 128 MFMA
    #define GLOOP(XF, ACC) { _Pragma("unroll")                                 \
        for (int kt = 0; kt < 8; kt++)                                         \
            _Pragma("unroll")                                                  \
            for (int jg = 0; jg < 8; jg++) {                                   \
                i64x2 bfr = *(const i64x2*)&L[(kt * 8 + jg) * 1024 + l16];     \
                ACC[jg] = MFMA8(XF[kt].x, bfr.x, ACC[jg]);                     \
                ACC[jg] = MFMA8(XF[kt].y, bfr.y, ACC[jg]);                     \
            } }

    // acc (C-layout) -> scr rowgroup RH with ReLU + 16B-chunk swizzle
    #define TOSCR(ACC, RH) { _Pragma("unroll")                                 \
        for (int jg = 0; jg < 8; jg++)                                         \
            _Pragma("unroll")                                                  \
            for (int q = 0; q < 4; q++) {                                      \
                int row = (RH) * 16 + kq * 4 + q;                              \
                scr[row * 128 + ((jg ^ (row & 7)) << 4) + r] =                 \
                    to_fp8(fmaxf(ACC[jg][q], 0.f));                            \
            } }

    // ---- xf: load once ----
    i64x2 xfA[8], xfB[8];
    #pragma unroll
    for (int kt = 0; kt < 8; kt++) {
        xfA[kt] = *(const i64x2*)(xb + (m0 + r) * 512 + kt * 64 + kq * 16);
        xfB[kt] = *(const i64x2*)(xb + (m0 + 16 + r) * 512 + kt * 64 + kq * 16);
    }

    i64x2 h1fA[8], h1fB[8];
    f32x4 yA = (f32x4){0.f, 0.f, 0.f, 0.f};
    f32x4 yB = (f32x4){0.f, 0.f, 0.f, 0.f};
    f32x4 acc[8];

    // ================= layer 1 =================
    #pragma unroll 1
    for (int nt = 0; nt < 4; nt++) {
        STAGEW(W1t, nt);
        asm volatile("s_waitcnt vmcnt(0)" ::: "memory");
        __builtin_amdgcn_s_barrier();
        #pragma unroll
        for (int jg = 0; jg < 8; jg++) acc[jg] = (f32x4){0.f, 0.f, 0.f, 0.f};
        GLOOP(xfA, acc);
        TOSCR(acc, 0);
        #pragma unroll
        for (int jg = 0; jg < 8; jg++) acc[jg] = (f32x4){0.f, 0.f, 0.f, 0.f};
        GLOOP(xfB, acc);
        TOSCR(acc, 1);
        __builtin_amdgcn_s_barrier();        // Wbuf fully consumed (ds drained by MFMA use)
        asm volatile("s_waitcnt lgkmcnt(0)" ::: "memory");
        SB0();
        #pragma unroll
        for (int t2 = 0; t2 < 2; t2++) {
            h1fA[nt * 2 + t2] = *(const i64x2*)
                &scr[r * 128 + (((t2 * 4 + kq) ^ (r & 7)) << 4)];
            h1fB[nt * 2 + t2] = *(const i64x2*)
                &scr[(16 + r) * 128 + (((t2 * 4 + kq) ^ (r & 7)) << 4)];
        }
        asm volatile("s_waitcnt lgkmcnt(0)" ::: "memory");   // reads done before reuse
        SB0();
    }

    // ================= layers 2 + 3 =================
    #pragma unroll 1
    for (int nt = 0; nt < 4; nt++) {
        STAGEW(W2t, nt);
        asm volatile("s_waitcnt vmcnt(0)" ::: "memory");
        __builtin_amdgcn_s_barrier();
        #pragma unroll
        for (int jg = 0; jg < 8; jg++) acc[jg] = (f32x4){0.f, 0.f, 0.f, 0.f};
        GLOOP(h1fA, acc);
        TOSCR(acc, 0);
        #pragma unroll
        for (int jg = 0; jg < 8; jg++) acc[jg] = (f32x4){0.f, 0.f, 0.f, 0.f};
        GLOOP(h1fB, acc);
        TOSCR(acc, 1);
        __builtin_amdgcn_s_barrier();
        asm volatile("s_waitcnt lgkmcnt(0)" ::: "memory");
        SB0();
        // fused layer 3: this tile's 128 cols of h2 = k-slice nt*128..+128
        #pragma unroll
        for (int t2 = 0; t2 < 2; t2++) {
            i64x2 a3A = *(const i64x2*)
                &scr[r * 128 + (((t2 * 4 + kq) ^ (r & 7)) << 4)];
            i64x2 a3B = *(const i64x2*)
                &scr[(16 + r) * 128 + (((t2 * 4 + kq) ^ (r & 7)) << 4)];
            i64x2 w3 = *(const i64x2*)(W3t + r * 512 + nt * 128 + t2 * 64 + kq * 16);
            yA = MFMA8(a3A.x, w3.x, yA);
            yA = MFMA8(a3A.y, w3.y, yA);
            yB = MFMA8(a3B.x, w3.x, yB);
            yB = MFMA8(a3B.y, w3.y, yB);
        }
        asm volatile("s_waitcnt lgkmcnt(0)" ::: "memory");
        SB0();
    }

    // ---- y store: direct, no atomics (full K per block) ----
    if (r < 10) {
        #pragma unroll
        for (int q = 0; q < 4; q++) {
            Y[(m0 + kq * 4 + q) * 10 + r]      = yA[q];
            Y[(m0 + 16 + kq * 4 + q) * 10 + r] = yB[q];
        }
    }
    #undef STAGEW
    #undef GLOOP
    #undef TOSCR
}

extern "C" void kernel_launch(void* const* d_in, const int* in_sizes, int n_in,
                              void* d_out, int out_size, void* d_ws, size_t ws_size,
                              hipStream_t stream) {
    const float* x   = (const float*)d_in[0];
    const float* mu1 = (const float*)d_in[1];
    const float* p1  = (const float*)d_in[2];
    const float* e1  = (const float*)d_in[3];
    const float* mu2 = (const float*)d_in[4];
    const float* p2  = (const float*)d_in[5];
    const float* e2  = (const float*)d_in[6];
    const float* mu3 = (const float*)d_in[7];
    const float* p3  = (const float*)d_in[8];
    const float* e3  = (const float*)d_in[9];
    float* out = (float*)d_out;

    const int B = 65536, D = 512, DO = 10;

    char* ws = (char*)d_ws;
    u8* Wt1 = (u8*)(ws);                       // 256 KB
    u8* Wt2 = (u8*)(ws + 262144);              // 256 KB
    u8* Wt3 = (u8*)(ws + 524288);              // 8 KB
    u8* xb  = (u8*)(ws + 1048576);             // 32 MB

    float* osc = out + (long)B * DO;

    hipMemsetAsync(osc, 0, 2 * sizeof(float), stream);
    hipLaunchKernelGGL(k_prep_all, dim3(528), dim3(256), 0, stream,
                       mu1, p1, e1, mu2, p2, e2, mu3, p3, e3, Wt1, Wt2, Wt3, osc);
    hipLaunchKernelGGL(k_cvt8, dim3(2048), dim3(256), 0, stream,
                       (const float4*)x, (uint2*)xb, B * D / 8);
    hipLaunchKernelGGL(k_f8, dim3(512), dim3(256), 0, stream,
                       xb, Wt1, Wt2, Wt3, out);
}

// Round 15
// 138.383 us; speedup vs baseline: 1.8923x; 1.1925x over previous
//
#include <hip/hip_runtime.h>
#include <hip/hip_bf16.h>
#include <stdint.h>

typedef unsigned char u8;
typedef unsigned int u32;
typedef unsigned long long u64;
typedef long i64;
typedef i64 i64x2 __attribute__((ext_vector_type(2)));
typedef float f32x4 __attribute__((ext_vector_type(4)));

#define LOGSQRT2PI 0.9189385332046727f
#define SB0() __builtin_amdgcn_sched_barrier(0)
#define MFMA8(A, B, C) __builtin_amdgcn_mfma_f32_16x16x32_fp8_fp8(A, B, C, 0, 0, 0)

__device__ __forceinline__ void gload_lds16(const void* g, void* l) {
    __builtin_amdgcn_global_load_lds((__attribute__((address_space(1))) void*)g,
                                     (__attribute__((address_space(3))) void*)l,
                                     16, 0, 0);
}

__device__ __forceinline__ u8 to_fp8(float v) {
    return (u8)(__builtin_amdgcn_cvt_pk_fp8_f32(v, 0.f, 0, false) & 0xff);
}

// 16 consecutive fp32 -> one 16-byte fp8 fragment (bytes k ascending)
__device__ __forceinline__ i64x2 cvt_frag(const float* base) {
    float4 v0 = *(const float4*)(base);
    float4 v1 = *(const float4*)(base + 4);
    float4 v2 = *(const float4*)(base + 8);
    float4 v3 = *(const float4*)(base + 12);
    u32 w0 = __builtin_amdgcn_cvt_pk_fp8_f32(v0.x, v0.y, 0, false);
    w0 = __builtin_amdgcn_cvt_pk_fp8_f32(v0.z, v0.w, (int)w0, true);
    u32 w1 = __builtin_amdgcn_cvt_pk_fp8_f32(v1.x, v1.y, 0, false);
    w1 = __builtin_amdgcn_cvt_pk_fp8_f32(v1.z, v1.w, (int)w1, true);
    u32 w2 = __builtin_amdgcn_cvt_pk_fp8_f32(v2.x, v2.y, 0, false);
    w2 = __builtin_amdgcn_cvt_pk_fp8_f32(v2.z, v2.w, (int)w2, true);
    u32 w3 = __builtin_amdgcn_cvt_pk_fp8_f32(v3.x, v3.y, 0, false);
    w3 = __builtin_amdgcn_cvt_pk_fp8_f32(v3.z, v3.w, (int)w3, true);
    i64x2 rr;
    rr.x = (i64)(((u64)w1 << 32) | (u64)w0);
    rr.y = (i64)(((u64)w3 << 32) | (u64)w2);
    return rr;
}

// ---- merged weight prep (r12-proven): W = mu+(1e-6+softplus(p))*eps ;
// ---- Wt[n][k] fp8 e4m3 ; lqw/lpw fp32-exact atomics ----
__device__ __forceinline__ void prep_body(const float* __restrict__ mu,
        const float* __restrict__ p, const float* __restrict__ eps,
        u8* __restrict__ Wt, int N, int Npad, float* __restrict__ osc,
        int vb, int nblocks) {
    int total = 512 * Npad;
    float lqw = 0.f, lpw = 0.f;
    for (int idx = vb * 256 + threadIdx.x; idx < total; idx += nblocks * 256) {
        int k = idx / Npad, n = idx - k * Npad;
        float w = 0.f;
        if (n < N) {
            int src = k * N + n;
            float m = mu[src], e = eps[src];
            float sd = 1e-6f + log1pf(expf(p[src]));
            w = m + sd * e;
            float z = (w - m) / sd;
            lqw += -LOGSQRT2PI - logf(sd) - 0.5f * z * z;
            lpw += -LOGSQRT2PI - 0.5f * w * w;
        }
        Wt[n * 512 + k] = to_fp8(w);
    }
    #pragma unroll
    for (int off = 32; off; off >>= 1) {
        lqw += __shfl_down(lqw, off);
        lpw += __shfl_down(lpw, off);
    }
    if ((threadIdx.x & 63) == 0) {
        atomicAdd(&osc[0], lqw);
        atomicAdd(&osc[1], lpw);
    }
}

__global__ void k_prep_all(const float* __restrict__ mu1, const float* __restrict__ p1,
                           const float* __restrict__ e1,
                           const float* __restrict__ mu2, const float* __restrict__ p2,
                           const float* __restrict__ e2,
                           const float* __restrict__ mu3, const float* __restrict__ p3,
                           const float* __restrict__ e3,
                           u8* __restrict__ Wt1, u8* __restrict__ Wt2,
                           u8* __restrict__ Wt3, float* __restrict__ osc) {
    int b = blockIdx.x;
    if (b < 256)      prep_body(mu1, p1, e1, Wt1, 512, 512, osc, b, 256);
    else if (b < 512) prep_body(mu2, p2, e2, Wt2, 512, 512, osc, b - 256, 256);
    else              prep_body(mu3, p3, e3, Wt3, 10,  16,  osc, b - 512, 16);
}

// ============================================================================
// Fully-fused fp8 3-layer kernel, v2 (r14 skeleton + 3 fixes).
//   Block = 4 waves x 32 rows; grid 512; LDS 80 KB (2x32KB Wbuf dbuf + 4x4KB
//   scr) -> 2 blocks/CU.
//   Fix 1: combined-rowgroup GLOOP — each B-frag ds_read_b128 feeds 4 MFMAs
//          (accA+accB) -> LDS reads halved vs r14 (was the issue-pipe limit).
//   Fix 2: 64-col W-tiles double-buffered — STAGE(nt+1 -> buf^1) issued at
//          phase start, vmcnt(0) at phase end after ~128 MFMAs: drain ~free.
//          Layer-1's last phase prefetches W2 tile 0.  No counted vmcnt.
//   Fix 3: x fp32 read directly (once per block) with inline cvt to the
//          permuted-k fp8 fragment layout -> k_cvt8 pass (160 MB) deleted.
//   h1 in registers (transposed via wave-private swizzled scr, r14-proven);
//   layer 3 fused per tile (w3 frag, 4 MFMA); y stored directly, no atomics.
// ============================================================================
__global__ __launch_bounds__(256, 2)
void k_f8(const float* __restrict__ X, const u8* __restrict__ W1t,
          const u8* __restrict__ W2t, const u8* __restrict__ W3t,
          float* __restrict__ Y) {
    __shared__ __align__(16) u8 L[81920];   // 2x32KB Wbuf + 4x4KB scr
    const int tid = threadIdx.x;
    const int l = tid & 63, w = tid >> 6;
    const int r = l & 15, kq = l >> 4;
    const int l16 = l * 16;
    const long m0 = (long)blockIdx.x * 128 + w * 32;
    u8* scr = &L[65536 + w * 4096];         // [32 rows][128B], 16B-chunk swizzle

    // stage one 64-col W tile (32 chunks x 1KB; chunk id = kt*4+jg): 8/thread
    #define STAGEW(WT, NT, BUF) { _Pragma("unroll")                            \
        for (int i = 0; i < 8; i++) {                                          \
            const int c = w * 8 + i;                                           \
            const int jg = c & 3, kt = c >> 2;                                 \
            gload_lds16((WT) + ((NT) * 64 + jg * 16 + r) * 512 + kt * 64 + kq * 16, \
                        &L[(BUF) * 32768 + c * 1024 + l16]);                   \
        } }

    // one tile's MFMAs, both rowgroups share each B-frag read (4 MFMA / read)
    #define GLOOP(BUF, XA, XB) { _Pragma("unroll")                             \
        for (int kt = 0; kt < 8; kt++)                                         \
            _Pragma("unroll")                                                  \
            for (int jg = 0; jg < 4; jg++) {                                   \
                i64x2 bfr = *(const i64x2*)&L[(BUF) * 32768 + (kt * 4 + jg) * 1024 + l16]; \
                accA[jg] = MFMA8(XA[kt].x, bfr.x, accA[jg]);                   \
                accA[jg] = MFMA8(XA[kt].y, bfr.y, accA[jg]);                   \
                accB[jg] = MFMA8(XB[kt].x, bfr.x, accB[jg]);                   \
                accB[jg] = MFMA8(XB[kt].y, bfr.y, accB[jg]);                   \
            } }

    // acc (C-layout) -> scr with ReLU; phys_chunk = jg ^ (row&7) (r14-proven)
    #define TOSCR() { _Pragma("unroll")                                        \
        for (int jg = 0; jg < 4; jg++)                                         \
            _Pragma("unroll")                                                  \
            for (int q = 0; q < 4; q++) {                                      \
                int rowA = kq * 4 + q;                                         \
                int rowB = 16 + kq * 4 + q;                                    \
                scr[rowA * 128 + ((jg ^ (rowA & 7)) << 4) + r] =               \
                    to_fp8(fmaxf(accA[jg][q], 0.f));                           \
                scr[rowB * 128 + ((jg ^ (rowB & 7)) << 4) + r] =               \
                    to_fp8(fmaxf(accB[jg][q], 0.f));                           \
            } }

    #define ZACC() { _Pragma("unroll")                                         \
        for (int jg = 0; jg < 4; jg++) {                                       \
            accA[jg] = (f32x4){0.f, 0.f, 0.f, 0.f};                            \
            accB[jg] = (f32x4){0.f, 0.f, 0.f, 0.f};                            \
        } }

    f32x4 accA[4], accB[4];
    i64x2 xfA[8], xfB[8];
    i64x2 h1fA[8], h1fB[8];
    f32x4 yA = (f32x4){0.f, 0.f, 0.f, 0.f};
    f32x4 yB = (f32x4){0.f, 0.f, 0.f, 0.f};

    // ---- prologue: stage W1 tile0; convert x inline (covers stage latency) ----
    STAGEW(W1t, 0, 0);
    #pragma unroll
    for (int kt = 0; kt < 8; kt++) {
        xfA[kt] = cvt_frag(X + (m0 + r) * 512 + kt * 64 + kq * 16);
        xfB[kt] = cvt_frag(X + (m0 + 16 + r) * 512 + kt * 64 + kq * 16);
    }
    asm volatile("s_waitcnt vmcnt(0)" ::: "memory");
    __builtin_amdgcn_s_barrier();

    // ================= layer 1 (8 x 64-col tiles) =================
    #pragma unroll 1
    for (int nt = 0; nt < 8; nt++) {
        const int buf = nt & 1;
        if (nt < 7) { STAGEW(W1t, nt + 1, buf ^ 1); }
        else        { STAGEW(W2t, 0, buf ^ 1); }     // cross-layer prefetch
        ZACC();
        GLOOP(buf, xfA, xfB);
        TOSCR();
        asm volatile("s_waitcnt lgkmcnt(0)" ::: "memory");
        SB0();
        h1fA[nt] = *(const i64x2*)&scr[r * 128 + ((kq ^ (r & 7)) << 4)];
        h1fB[nt] = *(const i64x2*)&scr[(16 + r) * 128 + ((kq ^ (r & 7)) << 4)];
        asm volatile("s_waitcnt lgkmcnt(0)" ::: "memory");  // scr reads done
        SB0();
        asm volatile("s_waitcnt vmcnt(0)" ::: "memory");    // next tile staged
        __builtin_amdgcn_s_barrier();
    }

    // ================= layers 2 + 3 (8 x 64-col tiles) =================
    #pragma unroll 1
    for (int nt = 0; nt < 8; nt++) {
        const int buf = (nt + 1) & 1;                // continues the alternation
        if (nt < 7) STAGEW(W2t, nt + 1, buf ^ 1);
        ZACC();
        GLOOP(buf, h1fA, h1fB);
        TOSCR();
        asm volatile("s_waitcnt lgkmcnt(0)" ::: "memory");
        SB0();
        // fused layer 3: this tile's 64 h2-cols = k-slice nt*64..+64
        {
            i64x2 a3A = *(const i64x2*)&scr[r * 128 + ((kq ^ (r & 7)) << 4)];
            i64x2 a3B = *(const i64x2*)&scr[(16 + r) * 128 + ((kq ^ (r & 7)) << 4)];
            i64x2 w3 = *(const i64x2*)(W3t + r * 512 + nt * 64 + kq * 16);
            yA = MFMA8(a3A.x, w3.x, yA);
            yA = MFMA8(a3A.y, w3.y, yA);
            yB = MFMA8(a3B.x, w3.x, yB);
            yB = MFMA8(a3B.y, w3.y, yB);
        }
        asm volatile("s_waitcnt lgkmcnt(0)" ::: "memory");
        SB0();
        if (nt < 7) { asm volatile("s_waitcnt vmcnt(0)" ::: "memory"); }
        __builtin_amdgcn_s_barrier();
    }

    // ---- y store: direct, no atomics ----
    if (r < 10) {
        #pragma unroll
        for (int q = 0; q < 4; q++) {
            Y[(m0 + kq * 4 + q) * 10 + r]      = yA[q];
            Y[(m0 + 16 + kq * 4 + q) * 10 + r] = yB[q];
        }
    }
    #undef STAGEW
    #undef GLOOP
    #undef TOSCR
    #undef ZACC
}

extern "C" void kernel_launch(void* const* d_in, const int* in_sizes, int n_in,
                              void* d_out, int out_size, void* d_ws, size_t ws_size,
                              hipStream_t stream) {
    const float* x   = (const float*)d_in[0];
    const float* mu1 = (const float*)d_in[1];
    const float* p1  = (const float*)d_in[2];
    const float* e1  = (const float*)d_in[3];
    const float* mu2 = (const float*)d_in[4];
    const float* p2  = (const float*)d_in[5];
    const float* e2  = (const float*)d_in[6];
    const float* mu3 = (const float*)d_in[7];
    const float* p3  = (const float*)d_in[8];
    const float* e3  = (const float*)d_in[9];
    float* out = (float*)d_out;

    const int B = 65536, DO = 10;

    char* ws = (char*)d_ws;
    u8* Wt1 = (u8*)(ws);            // 256 KB
    u8* Wt2 = (u8*)(ws + 262144);   // 256 KB
    u8* Wt3 = (u8*)(ws + 524288);   // 8 KB

    float* osc = out + (long)B * DO;

    hipMemsetAsync(osc, 0, 2 * sizeof(float), stream);
    hipLaunchKernelGGL(k_prep_all, dim3(528), dim3(256), 0, stream,
                       mu1, p1, e1, mu2, p2, e2, mu3, p3, e3, Wt1, Wt2, Wt3, osc);
    hipLaunchKernelGGL(k_f8, dim3(512), dim3(256), 0, stream,
                       x, Wt1, Wt2, Wt3, out);
}